// Round 4
// baseline (64.080 us; speedup 1.0000x reference)
//
#include <hip/hip_runtime.h>

// GraphConsis fused encoder + dot — round 3.
// B=4096, H=50, A=32, L=82, D=64, tables 100000x64.
//
// vs round 2 (53us main kernel, MSHR/latency-bound on scattered f32 gathers):
//  - per-call conversion of u2e/v2e to fp16 in d_ws (25.6MB): gather rows are
//    128B = 2 cache lines instead of 4 -> 2x fewer lines through the
//    miss-concurrency-bound path, and the footprint L2/L3-resides better
//    (latency down -> MSHR-bound throughput up).
//  - main kernel identical structure (4 entry-groups x 16 lanes, float4/half4
//    per lane, 4-step 16-lane xor reduce, lane==k rate-logit fold).
//  - runtime ws_size check: falls back to the proven f32 kernel if d_ws is
//    too small for the fp16 tables.

typedef _Float16 half4v __attribute__((ext_vector_type(4)));

#define NB 4096
#define NH 50
#define NA 32
#define ND 64
#define NROWS 100000

// ---------------- setup kernels ----------------

__global__ __launch_bounds__(256) void convert_f16(const float* __restrict__ src,
                                                   _Float16* __restrict__ dst,
                                                   int n4)
{
    int i = blockIdx.x * blockDim.x + threadIdx.x;
    const int stride = gridDim.x * blockDim.x;
    const float4* s4 = (const float4*)src;
    half4v* d4 = (half4v*)dst;
    for (; i < n4; i += stride) {
        const float4 v = s4[i];
        half4v h;
        h.x = (_Float16)v.x; h.y = (_Float16)v.y;
        h.z = (_Float16)v.z; h.w = (_Float16)v.w;
        d4[i] = h;
    }
}

__global__ void rlog_setup(const float* __restrict__ r2e,
                           const float* __restrict__ ra,
                           float* __restrict__ ws_rlog)
{
    const int lane = threadIdx.x;            // 64 threads
    const float ra_hi = ra[64 + lane];
    #pragma unroll
    for (int r = 0; r < 7; ++r) {
        float part = r2e[r * 64 + lane] * ra_hi;
        #pragma unroll
        for (int off = 32; off >= 1; off >>= 1)
            part += __shfl_xor(part, off);
        if (lane == 0) ws_rlog[r] = part;
    }
}

// ---------------- main kernel, fp16 gather path ----------------

__global__ __launch_bounds__(256, 8) void graphconsis_f16(
    const float* __restrict__ u2e, const float* __restrict__ v2e,
    const _Float16* __restrict__ uh, const _Float16* __restrict__ vh,
    const float* __restrict__ ra,
    const float* __restrict__ lin1_W, const float* __restrict__ lin1_b,
    const int* __restrict__ nodes_u, const int* __restrict__ nodes_v,
    const int* __restrict__ hist_u, const int* __restrict__ hist_ur,
    const int* __restrict__ adj_u,
    const int* __restrict__ hist_v, const int* __restrict__ hist_vr,
    const int* __restrict__ adj_v,
    const float* __restrict__ ws_rlog,
    float* __restrict__ out)
{
    __shared__ float lds_comb[4][128];
    __shared__ float ed[4][64];

    const int wid  = threadIdx.x >> 6;
    const int lane = threadIdx.x & 63;
    const int g    = lane >> 4;          // entry subgroup 0..3
    const int j    = lane & 15;          // dim-quad index
    const int side = wid >> 1;           // 0 = user, 1 = item
    const int b    = __builtin_amdgcn_readfirstlane(blockIdx.x * 2 + (wid & 1));

    const float* nodeTab      = side ? v2e : u2e;
    const _Float16* histTab   = side ? uh : vh;
    const _Float16* neighTab  = side ? vh : uh;
    const int* nodes = side ? nodes_v : nodes_u;
    const int* hn    = side ? hist_v  : hist_u;
    const int* hr    = side ? hist_vr : hist_ur;
    const int* adj   = side ? adj_v   : adj_u;

    const float4 ra4  = *(const float4*)(ra + 4 * j);
    const float rlog6 = ws_rlog[6];

    // preload history indices: lane (g,j) needs entry 4k+g at iteration k
    int hidx[13];
    #pragma unroll
    for (int k = 0; k < 13; ++k) {
        int l = 4 * k + g; if (l > NH - 1) l = NH - 1;
        hidx[k] = hn[b * NH + l];
    }
    // per-lane rate logit for history entry 4j+g (consumed at iter k==j)
    float rl0 = 0.f;
    { int l = 4 * j + g; if (l < NH) rl0 = ws_rlog[hr[b * NH + l]]; }

    float ssum = 0.f;
    float4 acc = make_float4(0.f, 0.f, 0.f, 0.f);

    // ---- history entries 0..47 (12 iters x 4 entries) ----
    #pragma unroll 4
    for (int k = 0; k < 12; ++k) {
        const half4v eh = *(const half4v*)(histTab + hidx[k] * ND + 4 * j);
        const float4 e = make_float4((float)eh.x, (float)eh.y, (float)eh.z, (float)eh.w);
        float part = e.x * ra4.x;
        part = fmaf(e.y, ra4.y, part);
        part = fmaf(e.z, ra4.z, part);
        part = fmaf(e.w, ra4.w, part);
        part += (j == k) ? rl0 : 0.f;
        part += __shfl_xor(part, 1);
        part += __shfl_xor(part, 2);
        part += __shfl_xor(part, 4);
        part += __shfl_xor(part, 8);
        const float p = __expf(part);
        ssum += p;
        acc.x = fmaf(p, e.x, acc.x);
        acc.y = fmaf(p, e.y, acc.y);
        acc.z = fmaf(p, e.z, acc.z);
        acc.w = fmaf(p, e.w, acc.w);
    }
    // ---- history tail: entries 48,49 on groups 0,1 ----
    {
        const half4v eh = *(const half4v*)(histTab + hidx[12] * ND + 4 * j);
        const float4 e = make_float4((float)eh.x, (float)eh.y, (float)eh.z, (float)eh.w);
        float part = e.x * ra4.x;
        part = fmaf(e.y, ra4.y, part);
        part = fmaf(e.z, ra4.z, part);
        part = fmaf(e.w, ra4.w, part);
        part += (j == 12) ? rl0 : 0.f;
        part += __shfl_xor(part, 1);
        part += __shfl_xor(part, 2);
        part += __shfl_xor(part, 4);
        part += __shfl_xor(part, 8);
        const float p = (g < 2) ? __expf(part) : 0.f;
        ssum += p;
        acc.x = fmaf(p, e.x, acc.x);
        acc.y = fmaf(p, e.y, acc.y);
        acc.z = fmaf(p, e.z, acc.z);
        acc.w = fmaf(p, e.w, acc.w);
    }
    // ---- adj entries 0..31 (8 iters x 4 entries), rate logit = rlog6 ----
    #pragma unroll 4
    for (int k = 0; k < 8; ++k) {
        const int idx = adj[b * NA + 4 * k + g];
        const half4v eh = *(const half4v*)(neighTab + idx * ND + 4 * j);
        const float4 e = make_float4((float)eh.x, (float)eh.y, (float)eh.z, (float)eh.w);
        float part = e.x * ra4.x;
        part = fmaf(e.y, ra4.y, part);
        part = fmaf(e.z, ra4.z, part);
        part = fmaf(e.w, ra4.w, part);
        part += __shfl_xor(part, 1);
        part += __shfl_xor(part, 2);
        part += __shfl_xor(part, 4);
        part += __shfl_xor(part, 8);
        const float p = __expf(part + rlog6);
        ssum += p;
        acc.x = fmaf(p, e.x, acc.x);
        acc.y = fmaf(p, e.y, acc.y);
        acc.z = fmaf(p, e.z, acc.z);
        acc.w = fmaf(p, e.w, acc.w);
    }

    // combine the 4 entry-groups
    ssum += __shfl_xor(ssum, 16);
    ssum += __shfl_xor(ssum, 32);
    acc.x += __shfl_xor(acc.x, 16); acc.x += __shfl_xor(acc.x, 32);
    acc.y += __shfl_xor(acc.y, 16); acc.y += __shfl_xor(acc.y, 32);
    acc.z += __shfl_xor(acc.z, 16); acc.z += __shfl_xor(acc.z, 32);
    acc.w += __shfl_xor(acc.w, 16); acc.w += __shfl_xor(acc.w, 32);

    const float inv = 1.0f / ssum;
    const float4 nf4 = *(const float4*)(nodeTab + nodes[b] * ND + 4 * j);

    if (g == 0) {
        *(float4*)&lds_comb[wid][4 * j] = nf4;
        float4 n4 = make_float4(acc.x * inv, acc.y * inv, acc.z * inv, acc.w * inv);
        *(float4*)&lds_comb[wid][64 + 4 * j] = n4;
    }

    // out_j = relu(b_j + sum_k W[j][k] * comb[k]); lane = output j
    float o = lin1_b[lane];
    const float4* W4 = (const float4*)(lin1_W + lane * 128);
    const float4* C4 = (const float4*)lds_comb[wid];
    #pragma unroll 8
    for (int kk = 0; kk < 32; ++kk) {
        const float4 w = W4[kk];
        const float4 c = C4[kk];
        o = fmaf(w.x, c.x, o);
        o = fmaf(w.y, c.y, o);
        o = fmaf(w.z, c.z, o);
        o = fmaf(w.w, c.w, o);
    }
    const float evec = fmaxf(o, 0.f);

    ed[wid][lane] = evec;
    __syncthreads();

    if (wid < 2) {
        float prod = ed[wid][lane] * ed[wid + 2][lane];
        #pragma unroll
        for (int off = 32; off >= 1; off >>= 1)
            prod += __shfl_xor(prod, off);
        if (lane == 0) out[blockIdx.x * 2 + wid] = prod;
    }
}

// ---------------- fallback f32 main kernel (round-2 proven) ----------------

__global__ __launch_bounds__(256, 8) void graphconsis_f32(
    const float* __restrict__ u2e, const float* __restrict__ v2e,
    const float* __restrict__ ra,
    const float* __restrict__ lin1_W, const float* __restrict__ lin1_b,
    const int* __restrict__ nodes_u, const int* __restrict__ nodes_v,
    const int* __restrict__ hist_u, const int* __restrict__ hist_ur,
    const int* __restrict__ adj_u,
    const int* __restrict__ hist_v, const int* __restrict__ hist_vr,
    const int* __restrict__ adj_v,
    const float* __restrict__ ws_rlog,
    float* __restrict__ out)
{
    __shared__ float lds_comb[4][128];
    __shared__ float ed[4][64];

    const int wid  = threadIdx.x >> 6;
    const int lane = threadIdx.x & 63;
    const int g    = lane >> 4;
    const int j    = lane & 15;
    const int side = wid >> 1;
    const int b    = __builtin_amdgcn_readfirstlane(blockIdx.x * 2 + (wid & 1));

    const float* nodeTab  = side ? v2e : u2e;
    const float* histTab  = side ? u2e : v2e;
    const float* neighTab = side ? v2e : u2e;
    const int* nodes = side ? nodes_v : nodes_u;
    const int* hn    = side ? hist_v  : hist_u;
    const int* hr    = side ? hist_vr : hist_ur;
    const int* adj   = side ? adj_v   : adj_u;

    const float4 ra4  = *(const float4*)(ra + 4 * j);
    const float rlog6 = ws_rlog[6];

    int hidx[13];
    #pragma unroll
    for (int k = 0; k < 13; ++k) {
        int l = 4 * k + g; if (l > NH - 1) l = NH - 1;
        hidx[k] = hn[b * NH + l];
    }
    float rl0 = 0.f;
    { int l = 4 * j + g; if (l < NH) rl0 = ws_rlog[hr[b * NH + l]]; }

    float ssum = 0.f;
    float4 acc = make_float4(0.f, 0.f, 0.f, 0.f);

    #pragma unroll 4
    for (int k = 0; k < 12; ++k) {
        const float4 e = *(const float4*)(histTab + hidx[k] * ND + 4 * j);
        float part = e.x * ra4.x;
        part = fmaf(e.y, ra4.y, part);
        part = fmaf(e.z, ra4.z, part);
        part = fmaf(e.w, ra4.w, part);
        part += (j == k) ? rl0 : 0.f;
        part += __shfl_xor(part, 1);
        part += __shfl_xor(part, 2);
        part += __shfl_xor(part, 4);
        part += __shfl_xor(part, 8);
        const float p = __expf(part);
        ssum += p;
        acc.x = fmaf(p, e.x, acc.x);
        acc.y = fmaf(p, e.y, acc.y);
        acc.z = fmaf(p, e.z, acc.z);
        acc.w = fmaf(p, e.w, acc.w);
    }
    {
        const float4 e = *(const float4*)(histTab + hidx[12] * ND + 4 * j);
        float part = e.x * ra4.x;
        part = fmaf(e.y, ra4.y, part);
        part = fmaf(e.z, ra4.z, part);
        part = fmaf(e.w, ra4.w, part);
        part += (j == 12) ? rl0 : 0.f;
        part += __shfl_xor(part, 1);
        part += __shfl_xor(part, 2);
        part += __shfl_xor(part, 4);
        part += __shfl_xor(part, 8);
        const float p = (g < 2) ? __expf(part) : 0.f;
        ssum += p;
        acc.x = fmaf(p, e.x, acc.x);
        acc.y = fmaf(p, e.y, acc.y);
        acc.z = fmaf(p, e.z, acc.z);
        acc.w = fmaf(p, e.w, acc.w);
    }
    #pragma unroll 4
    for (int k = 0; k < 8; ++k) {
        const int idx = adj[b * NA + 4 * k + g];
        const float4 e = *(const float4*)(neighTab + idx * ND + 4 * j);
        float part = e.x * ra4.x;
        part = fmaf(e.y, ra4.y, part);
        part = fmaf(e.z, ra4.z, part);
        part = fmaf(e.w, ra4.w, part);
        part += __shfl_xor(part, 1);
        part += __shfl_xor(part, 2);
        part += __shfl_xor(part, 4);
        part += __shfl_xor(part, 8);
        const float p = __expf(part + rlog6);
        ssum += p;
        acc.x = fmaf(p, e.x, acc.x);
        acc.y = fmaf(p, e.y, acc.y);
        acc.z = fmaf(p, e.z, acc.z);
        acc.w = fmaf(p, e.w, acc.w);
    }

    ssum += __shfl_xor(ssum, 16);
    ssum += __shfl_xor(ssum, 32);
    acc.x += __shfl_xor(acc.x, 16); acc.x += __shfl_xor(acc.x, 32);
    acc.y += __shfl_xor(acc.y, 16); acc.y += __shfl_xor(acc.y, 32);
    acc.z += __shfl_xor(acc.z, 16); acc.z += __shfl_xor(acc.z, 32);
    acc.w += __shfl_xor(acc.w, 16); acc.w += __shfl_xor(acc.w, 32);

    const float inv = 1.0f / ssum;
    const float4 nf4 = *(const float4*)(nodeTab + nodes[b] * ND + 4 * j);

    if (g == 0) {
        *(float4*)&lds_comb[wid][4 * j] = nf4;
        float4 n4 = make_float4(acc.x * inv, acc.y * inv, acc.z * inv, acc.w * inv);
        *(float4*)&lds_comb[wid][64 + 4 * j] = n4;
    }

    float o = lin1_b[lane];
    const float4* W4 = (const float4*)(lin1_W + lane * 128);
    const float4* C4 = (const float4*)lds_comb[wid];
    #pragma unroll 8
    for (int kk = 0; kk < 32; ++kk) {
        const float4 w = W4[kk];
        const float4 c = C4[kk];
        o = fmaf(w.x, c.x, o);
        o = fmaf(w.y, c.y, o);
        o = fmaf(w.z, c.z, o);
        o = fmaf(w.w, c.w, o);
    }
    const float evec = fmaxf(o, 0.f);

    ed[wid][lane] = evec;
    __syncthreads();

    if (wid < 2) {
        float prod = ed[wid][lane] * ed[wid + 2][lane];
        #pragma unroll
        for (int off = 32; off >= 1; off >>= 1)
            prod += __shfl_xor(prod, off);
        if (lane == 0) out[blockIdx.x * 2 + wid] = prod;
    }
}

// ---------------- launch ----------------

extern "C" void kernel_launch(void* const* d_in, const int* in_sizes, int n_in,
                              void* d_out, int out_size, void* d_ws, size_t ws_size,
                              hipStream_t stream)
{
    const float* u2e     = (const float*)d_in[0];
    const float* v2e     = (const float*)d_in[1];
    const float* r2e     = (const float*)d_in[2];
    const float* ra      = (const float*)d_in[3];
    // d_in[4] agg_W, d_in[5] agg_b: dead code in the reference
    const float* lin1_W  = (const float*)d_in[6];
    const float* lin1_b  = (const float*)d_in[7];
    const int* nodes_u   = (const int*)d_in[8];
    const int* nodes_v   = (const int*)d_in[9];
    const int* hist_u    = (const int*)d_in[10];
    const int* hist_ur   = (const int*)d_in[11];
    const int* adj_u     = (const int*)d_in[12];
    const int* hist_v    = (const int*)d_in[13];
    const int* hist_vr   = (const int*)d_in[14];
    const int* adj_v     = (const int*)d_in[15];
    float* out = (float*)d_out;

    const size_t tab_elems = (size_t)NROWS * ND;           // 6.4M
    const size_t f16_bytes = tab_elems * sizeof(_Float16); // 12.8MB per table
    const size_t need = 2 * f16_bytes + 64;

    if (ws_size >= need) {
        _Float16* uh = (_Float16*)d_ws;
        _Float16* vh = (_Float16*)((char*)d_ws + f16_bytes);
        float* ws_rlog = (float*)((char*)d_ws + 2 * f16_bytes);
        const int n4 = (int)(tab_elems / 4);
        hipLaunchKernelGGL(convert_f16, dim3(2048), dim3(256), 0, stream, u2e, uh, n4);
        hipLaunchKernelGGL(convert_f16, dim3(2048), dim3(256), 0, stream, v2e, vh, n4);
        hipLaunchKernelGGL(rlog_setup, dim3(1), dim3(64), 0, stream, r2e, ra, ws_rlog);
        hipLaunchKernelGGL(graphconsis_f16, dim3(NB / 2), dim3(256), 0, stream,
                           u2e, v2e, uh, vh, ra, lin1_W, lin1_b,
                           nodes_u, nodes_v, hist_u, hist_ur, adj_u,
                           hist_v, hist_vr, adj_v, ws_rlog, out);
    } else {
        float* ws_rlog = (float*)d_ws;
        hipLaunchKernelGGL(rlog_setup, dim3(1), dim3(64), 0, stream, r2e, ra, ws_rlog);
        hipLaunchKernelGGL(graphconsis_f32, dim3(NB / 2), dim3(256), 0, stream,
                           u2e, v2e, ra, lin1_W, lin1_b,
                           nodes_u, nodes_v, hist_u, hist_ur, adj_u,
                           hist_v, hist_vr, adj_v, ws_rlog, out);
    }
}

// Round 5
// 61.475 us; speedup vs baseline: 1.0424x; 1.0424x over previous
//
#include <hip/hip_runtime.h>

// GraphConsis fused encoder + dot — round 4.
// B=4096, H=50, A=32, L=82, D=64, tables 100000x64 f32.
//
// vs round 3 (45us f16 main + 18us conversion; diagnosis: latency-bound at
// MLP~4 loads/wave, VGPR=28 — data format nearly irrelevant):
//  - back to f32 tables: no conversion kernels, no workspace, absmax ~0
//  - prefetch-ALL: the 21 row-gathers (13 hist + 8 adj) + node row issue
//    back-to-back into register arrays before any consumption -> per-wave
//    outstanding loads 4 -> 22 (VGPR ~120, occupancy 4 waves/SIMD traded
//    deliberately for 5x memory-level parallelism)
//  - rlog folded into main kernel: wave 0 computes the 7 rate logits into
//    LDS while all waves' gathers are in flight; the barrier's implicit
//    vmcnt(0) drain doubles as the prefetch join point. Single dispatch.

#define NB 4096
#define NH 50
#define NA 32
#define ND 64

__global__ __launch_bounds__(256) void graphconsis_main(
    const float* __restrict__ u2e, const float* __restrict__ v2e,
    const float* __restrict__ r2e, const float* __restrict__ ra,
    const float* __restrict__ lin1_W, const float* __restrict__ lin1_b,
    const int* __restrict__ nodes_u, const int* __restrict__ nodes_v,
    const int* __restrict__ hist_u, const int* __restrict__ hist_ur,
    const int* __restrict__ adj_u,
    const int* __restrict__ hist_v, const int* __restrict__ hist_vr,
    const int* __restrict__ adj_v,
    float* __restrict__ out)
{
    __shared__ float rlog_lds[8];
    __shared__ float lds_comb[4][128];
    __shared__ float ed[4][64];

    const int wid  = threadIdx.x >> 6;
    const int lane = threadIdx.x & 63;
    const int g    = lane >> 4;          // entry subgroup 0..3
    const int j    = lane & 15;          // dim-quad index
    const int side = wid >> 1;           // 0 = user, 1 = item
    const int b    = __builtin_amdgcn_readfirstlane(blockIdx.x * 2 + (wid & 1));

    const float* nodeTab  = side ? v2e : u2e;
    const float* histTab  = side ? u2e : v2e;
    const float* neighTab = side ? v2e : u2e;
    const int* nodes = side ? nodes_v : nodes_u;
    const int* hn    = side ? hist_v  : hist_u;
    const int* hr    = side ? hist_vr : hist_ur;
    const int* adj   = side ? adj_v   : adj_u;

    const float4 ra4 = *(const float4*)(ra + 4 * j);

    // ---- index preload (entry 4k+g at iteration k) ----
    int hidx[13];
    #pragma unroll
    for (int k = 0; k < 13; ++k) {
        int l = 4 * k + g; if (l > NH - 1) l = NH - 1;
        hidx[k] = hn[b * NH + l];
    }
    int aidx[8];
    #pragma unroll
    for (int k = 0; k < 8; ++k)
        aidx[k] = adj[b * NA + 4 * k + g];
    // rate index for history entry 4j+g (consumed at iter k==j); LDS lookup
    // deferred until after the barrier.
    int hrv = 7;
    { int l = 4 * j + g; if (l < NH) hrv = hr[b * NH + l]; }

    // ---- prefetch ALL embedding rows into registers (max MLP) ----
    const float4 nf4 = *(const float4*)(nodeTab + nodes[b] * ND + 4 * j);
    float4 rh[13];
    #pragma unroll
    for (int k = 0; k < 13; ++k)
        rh[k] = *(const float4*)(histTab + hidx[k] * ND + 4 * j);
    float4 raj[8];
    #pragma unroll
    for (int k = 0; k < 8; ++k)
        raj[k] = *(const float4*)(neighTab + aidx[k] * ND + 4 * j);

    // ---- wave 0: rate logits into LDS while gathers are in flight ----
    if (wid == 0) {
        const float ra_hi = ra[64 + lane];
        #pragma unroll
        for (int r = 0; r < 7; ++r) {
            float part = r2e[r * 64 + lane] * ra_hi;
            #pragma unroll
            for (int off = 32; off >= 1; off >>= 1)
                part += __shfl_xor(part, off);
            if (lane == 0) rlog_lds[r] = part;
        }
        if (lane == 0) rlog_lds[7] = 0.f;   // clamp slot for masked lanes
    }
    __syncthreads();   // joins wave0's rlog AND (vmcnt drain) all prefetches

    const float rl0   = rlog_lds[hrv];
    const float rlog6 = rlog_lds[6];

    float ssum = 0.f;
    float4 acc = make_float4(0.f, 0.f, 0.f, 0.f);

    // ---- history entries 0..47 ----
    #pragma unroll
    for (int k = 0; k < 12; ++k) {
        const float4 e = rh[k];
        float part = e.x * ra4.x;
        part = fmaf(e.y, ra4.y, part);
        part = fmaf(e.z, ra4.z, part);
        part = fmaf(e.w, ra4.w, part);
        part += (j == k) ? rl0 : 0.f;
        part += __shfl_xor(part, 1);
        part += __shfl_xor(part, 2);
        part += __shfl_xor(part, 4);
        part += __shfl_xor(part, 8);
        const float p = __expf(part);
        ssum += p;
        acc.x = fmaf(p, e.x, acc.x);
        acc.y = fmaf(p, e.y, acc.y);
        acc.z = fmaf(p, e.z, acc.z);
        acc.w = fmaf(p, e.w, acc.w);
    }
    // ---- history tail: entries 48,49 live on groups 0,1 ----
    {
        const float4 e = rh[12];
        float part = e.x * ra4.x;
        part = fmaf(e.y, ra4.y, part);
        part = fmaf(e.z, ra4.z, part);
        part = fmaf(e.w, ra4.w, part);
        part += (j == 12) ? rl0 : 0.f;
        part += __shfl_xor(part, 1);
        part += __shfl_xor(part, 2);
        part += __shfl_xor(part, 4);
        part += __shfl_xor(part, 8);
        const float p = (g < 2) ? __expf(part) : 0.f;
        ssum += p;
        acc.x = fmaf(p, e.x, acc.x);
        acc.y = fmaf(p, e.y, acc.y);
        acc.z = fmaf(p, e.z, acc.z);
        acc.w = fmaf(p, e.w, acc.w);
    }
    // ---- adj entries 0..31 (rate logit = rlog6) ----
    #pragma unroll
    for (int k = 0; k < 8; ++k) {
        const float4 e = raj[k];
        float part = e.x * ra4.x;
        part = fmaf(e.y, ra4.y, part);
        part = fmaf(e.z, ra4.z, part);
        part = fmaf(e.w, ra4.w, part);
        part += __shfl_xor(part, 1);
        part += __shfl_xor(part, 2);
        part += __shfl_xor(part, 4);
        part += __shfl_xor(part, 8);
        const float p = __expf(part + rlog6);
        ssum += p;
        acc.x = fmaf(p, e.x, acc.x);
        acc.y = fmaf(p, e.y, acc.y);
        acc.z = fmaf(p, e.z, acc.z);
        acc.w = fmaf(p, e.w, acc.w);
    }

    // combine the 4 entry-groups
    ssum += __shfl_xor(ssum, 16);
    ssum += __shfl_xor(ssum, 32);
    acc.x += __shfl_xor(acc.x, 16); acc.x += __shfl_xor(acc.x, 32);
    acc.y += __shfl_xor(acc.y, 16); acc.y += __shfl_xor(acc.y, 32);
    acc.z += __shfl_xor(acc.z, 16); acc.z += __shfl_xor(acc.z, 32);
    acc.w += __shfl_xor(acc.w, 16); acc.w += __shfl_xor(acc.w, 32);

    const float inv = 1.0f / ssum;

    // comb -> own LDS slice (wave-local, wave-synchronous: no barrier)
    if (g == 0) {
        *(float4*)&lds_comb[wid][4 * j] = nf4;
        float4 n4 = make_float4(acc.x * inv, acc.y * inv, acc.z * inv, acc.w * inv);
        *(float4*)&lds_comb[wid][64 + 4 * j] = n4;
    }

    // out_j = relu(b_j + sum_k W[j][k] * comb[k]); lane = output j
    float o = lin1_b[lane];
    const float4* W4 = (const float4*)(lin1_W + lane * 128);
    const float4* C4 = (const float4*)lds_comb[wid];
    #pragma unroll 8
    for (int kk = 0; kk < 32; ++kk) {
        const float4 w = W4[kk];
        const float4 c = C4[kk];
        o = fmaf(w.x, c.x, o);
        o = fmaf(w.y, c.y, o);
        o = fmaf(w.z, c.z, o);
        o = fmaf(w.w, c.w, o);
    }
    const float evec = fmaxf(o, 0.f);

    ed[wid][lane] = evec;
    __syncthreads();

    if (wid < 2) {
        float prod = ed[wid][lane] * ed[wid + 2][lane];
        #pragma unroll
        for (int off = 32; off >= 1; off >>= 1)
            prod += __shfl_xor(prod, off);
        if (lane == 0) out[blockIdx.x * 2 + wid] = prod;
    }
}

extern "C" void kernel_launch(void* const* d_in, const int* in_sizes, int n_in,
                              void* d_out, int out_size, void* d_ws, size_t ws_size,
                              hipStream_t stream)
{
    const float* u2e     = (const float*)d_in[0];
    const float* v2e     = (const float*)d_in[1];
    const float* r2e     = (const float*)d_in[2];
    const float* ra      = (const float*)d_in[3];
    // d_in[4] agg_W, d_in[5] agg_b: dead code in the reference
    const float* lin1_W  = (const float*)d_in[6];
    const float* lin1_b  = (const float*)d_in[7];
    const int* nodes_u   = (const int*)d_in[8];
    const int* nodes_v   = (const int*)d_in[9];
    const int* hist_u    = (const int*)d_in[10];
    const int* hist_ur   = (const int*)d_in[11];
    const int* adj_u     = (const int*)d_in[12];
    const int* hist_v    = (const int*)d_in[13];
    const int* hist_vr   = (const int*)d_in[14];
    const int* adj_v     = (const int*)d_in[15];
    float* out = (float*)d_out;

    hipLaunchKernelGGL(graphconsis_main, dim3(NB / 2), dim3(256), 0, stream,
                       u2e, v2e, r2e, ra, lin1_W, lin1_b,
                       nodes_u, nodes_v, hist_u, hist_ur, adj_u,
                       hist_v, hist_vr, adj_v, out);
}